// Round 9
// baseline (467.292 us; speedup 1.0000x reference)
//
#include <hip/hip_runtime.h>

#define H_    200
#define W_    200
#define C_    256
#define NROI  4096
#define KDIM  12544   // 49*256
#define HID_  256
#define NCLS_ 21
#define NTASK (NROI * 49)
#define NSPLIT 16
#define NQ    196     // 49 cells * 4 quarters (64ch each)
#define NHEAD 112     // 21 + 84, padded to 7*16

typedef __bf16 bf16x8 __attribute__((ext_vector_type(8)));
typedef float  f32x4  __attribute__((ext_vector_type(4)));
typedef unsigned short u16x8 __attribute__((ext_vector_type(8)));

__device__ __forceinline__ unsigned short f2bf(float f) {
  unsigned u = __float_as_uint(f);
  return (unsigned short)((u + 0x7FFFu + ((u >> 16) & 1u)) >> 16);  // RNE, no NaN inputs
}
__device__ __forceinline__ float bf2f(unsigned short u) {
  return __uint_as_float(((unsigned)u) << 16);
}
__device__ __forceinline__ void gload16(const void* g, void* l) {
  __builtin_amdgcn_global_load_lds((const __attribute__((address_space(1))) unsigned int*)g,
                                   (__attribute__((address_space(3))) unsigned int*)l, 16, 0, 0);
}

// ================= prep_all: cvt + transpose_w1 + wprep + prep_bases =================
#define NB_CVT   2048
#define NB_TRN   3136   // 392 * 8
#define NB_WPR   112
#define NB_BAS   784    // NTASK/256

__global__ __launch_bounds__(256) void prep_all(
    const float* __restrict__ F, unsigned short* __restrict__ Fb,
    const float* __restrict__ W1, unsigned short* __restrict__ BT,
    const float* __restrict__ Wc, const float* __restrict__ bc,
    const float* __restrict__ Wb, const float* __restrict__ bb,
    unsigned short* __restrict__ WT, float* __restrict__ Wbias,
    const float* __restrict__ rois, short4* __restrict__ Bases) {
  __shared__ float tile[32][33];
  const int b = blockIdx.x;
  const int tid = threadIdx.x;

  if (b < NB_CVT) {
    // ---- features f32 -> bf16 ----
    const int n4 = (H_ * W_ * C_) / 4;
    for (int i = b * 256 + tid; i < n4; i += NB_CVT * 256) {
      float4 v = ((const float4*)F)[i];
      ushort4 o;
      o.x = f2bf(v.x); o.y = f2bf(v.y); o.z = f2bf(v.z); o.w = f2bf(v.w);
      ((ushort4*)Fb)[i] = o;
    }
  } else if (b < NB_CVT + NB_TRN) {
    // ---- W1 (K x N) -> BT (N x K) bf16 ----
    const int id = b - NB_CVT;
    const int k0 = (id % 392) * 32;
    const int n0 = (id / 392) * 32;
    const int tx = tid & 31;
    const int ty = tid >> 5;
#pragma unroll
    for (int i = 0; i < 4; ++i)
      tile[ty + 8 * i][tx] = W1[(size_t)(k0 + ty + 8 * i) * HID_ + n0 + tx];
    __syncthreads();
#pragma unroll
    for (int i = 0; i < 4; ++i) {
      const int n = ty + 8 * i;
      BT[(size_t)(n0 + n) * KDIM + k0 + tx] = f2bf(tile[tx][n]);
    }
  } else if (b < NB_CVT + NB_TRN + NB_WPR) {
    // ---- heads weights pack ----
    const int n = b - (NB_CVT + NB_TRN);
    const int k = tid;
    float v = 0.f;
    if (n < 21)       v = Wc[(size_t)k * NCLS_ + n];
    else if (n < 105) v = Wb[(size_t)k * (NCLS_ * 4) + (n - 21)];
    WT[(size_t)n * HID_ + k] = f2bf(v);
    if (k == 0) Wbias[n] = (n < 21) ? bc[n] : ((n < 105) ? bb[n - 21] : 0.f);
  } else {
    // ---- per-task gather bases ----
    const int task = (b - (NB_CVT + NB_TRN + NB_WPR)) * 256 + tid;
    const int roi  = task / 49;
    const int cell = task - roi * 49;
    const int py = cell / 7;
    const int px = cell - py * 7;

    float4 r = ((const float4*)rois)[roi];
    const float y1 = fminf(r.x, r.z), y2 = fmaxf(r.x, r.z);
    const float x1 = fminf(r.y, r.w), x2 = fmaxf(r.y, r.w);
    const float dy = __fsub_rn(y2, y1), dx = __fsub_rn(x2, x1);

    short v[4];
#pragma unroll
    for (int g = 0; g < 2; ++g) {
      float tyv = __fdiv_rn(__fadd_rn((float)(2 * py + g), 0.5f), 14.0f);
      float txv = __fdiv_rn(__fadd_rn((float)(2 * px + g), 0.5f), 14.0f);
      float ys = __fadd_rn(y1, __fmul_rn(dy, tyv));
      float xs = __fadd_rn(x1, __fmul_rn(dx, txv));
      int yi = (int)rintf(__fmul_rn(ys, 199.0f));
      int xi = (int)rintf(__fmul_rn(xs, 199.0f));
      v[g]     = (short)min(max(yi, 0), H_ - 1);
      v[2 + g] = (short)min(max(xi, 0), W_ - 1);
    }
    Bases[task] = make_short4(v[0], v[1], v[2], v[3]);
  }
}

// ============ gemm_fused: ROI-pool fused into A-staging; Hp[split] = X@W1 slice ============
// 64x256 tile, 512 threads (8 waves, 2x4 of 32x64). SINGLE-buffered As (8 KB) + Bs (32 KB)
// = 40 KB LDS -> 4 blocks/CU (32 waves, 100% occ). K-split 16 by quarters (64ch units).
__global__ __launch_bounds__(512, 8) void gemm_fused(
    const unsigned short* __restrict__ Fb, const short4* __restrict__ Bases,
    const unsigned short* __restrict__ BT, unsigned short* __restrict__ Hp) {
  __shared__ __align__(16) unsigned char As[64 * 128];   // 8 KB
  __shared__ __align__(16) unsigned char Bs[256 * 128];  // 32 KB
  const int tid  = threadIdx.x;
  const int lane = tid & 63;
  const int wi   = tid >> 6;              // wave 0..7
  const int wr   = wi >> 2, wc = wi & 3;  // 2x4 wave grid, each 32x64

  const int split = blockIdx.x & 15;      // blockIdx%8 == split%8 -> B slice per XCD
  const int bm    = blockIdx.x >> 4;      // 0..63
  const int q0 = (NQ * split) >> 4;       // first quarter (64ch) of this split
  const int q1 = (NQ * (split + 1)) >> 4;
  const int nt = q1 - q0;                 // 12 or 13 iterations (BK=64)

  // ---- A gather assignment: thread stages row rl, 8-ch group g8 (4 loads/iter) ----
  const int rl = tid >> 3;                // 0..63
  const int g8 = tid & 7;
  const short4* bp = Bases + (size_t)(bm * 64 + rl) * 49;
  const int awb = rl * 128 + ((g8 * 16) ^ ((rl & 7) << 4));
  const unsigned short* fbg = Fb + g8 * 8;

  const unsigned short *p00, *p01, *p10, *p11;
#define SETPTRS(bv)                                        \
  p00 = fbg + ((size_t)((bv).x * W_ + (bv).z) * C_);       \
  p01 = fbg + ((size_t)((bv).x * W_ + (bv).w) * C_);       \
  p10 = fbg + ((size_t)((bv).y * W_ + (bv).z) * C_);       \
  p11 = fbg + ((size_t)((bv).y * W_ + (bv).w) * C_)

  // ---- B staging: linear LDS dest, inverse-swizzled global source ----
  const int srow  = lane >> 3;
  const int sbyte = ((lane & 7) << 4) ^ (srow << 4);
  const size_t kbase = (size_t)q0 * 64 + (sbyte >> 1);
  const unsigned short* gB[4];
  int lBo[4];
#pragma unroll
  for (int r = 0; r < 4; ++r) {
    const int row = r * 64 + wi * 8;
    gB[r]  = BT + (size_t)(row + srow) * KDIM + kbase;
    lBo[r] = row * 128;
  }

  // ---- LDS fragment-read offsets (swizzled) ----
  int aoff[2][2], boff[4][2];
#pragma unroll
  for (int kf = 0; kf < 2; ++kf) {
    const int kb = kf * 64 + ((lane >> 4) << 4);
#pragma unroll
    for (int m = 0; m < 2; ++m) {
      const int arow = wr * 32 + m * 16 + (lane & 15);
      aoff[m][kf] = arow * 128 + (kb ^ ((arow & 7) << 4));
    }
#pragma unroll
    for (int n = 0; n < 4; ++n) {
      const int brow = wc * 64 + n * 16 + (lane & 15);
      boff[n][kf] = brow * 128 + (kb ^ ((brow & 7) << 4));
    }
  }

  f32x4 acc[2][4] = {};

  // ---- prologue: stage tile 0 (quarter q0) ----
  short4 nb;
  {
    const int cell0 = q0 >> 2;
    nb = bp[cell0];
    SETPTRS(nb);
    const int pc = (cell0 + 1 < 49) ? cell0 + 1 : 48;
    nb = bp[pc];                             // prefetch next cell's bases
#pragma unroll
    for (int r = 0; r < 4; ++r) gload16(gB[r], &Bs[lBo[r]]);   // B tile 0
    const int qo0 = (q0 & 3) * 64;
    u16x8 a0 = *(const u16x8*)(p00 + qo0), a1 = *(const u16x8*)(p01 + qo0);
    u16x8 a2 = *(const u16x8*)(p10 + qo0), a3 = *(const u16x8*)(p11 + qo0);
    u16x8 o0;
#pragma unroll
    for (int j = 0; j < 8; ++j) {
      float m0 = fmaxf(fmaxf(bf2f(a0[j]), bf2f(a1[j])), fmaxf(bf2f(a2[j]), bf2f(a3[j])));
      o0[j] = (unsigned short)(__float_as_uint(m0) >> 16);
    }
    *(u16x8*)(&As[awb]) = o0;
  }

  for (int t = 0; t < nt; ++t) {
    __syncthreads();   // bar1: tile t staged (A ds_writes lgkm-drained, B gloads vmcnt-drained)

    const int pre = (t + 1 < nt);
    u16x8 a0, a1, a2, a3;
    if (pre) {
      const int qn = q0 + t + 1;
      if ((qn & 3) == 0) {                   // new cell: use prefetched bases
        SETPTRS(nb);
        const int pc = ((qn >> 2) + 1 < 49) ? (qn >> 2) + 1 : 48;
        nb = bp[pc];
      }
      const int qo = (qn & 3) * 64;
      a0 = *(const u16x8*)(p00 + qo); a1 = *(const u16x8*)(p01 + qo);
      a2 = *(const u16x8*)(p10 + qo); a3 = *(const u16x8*)(p11 + qo);
    }

    // ---- MFMA on tile t (hides A-gather latency for t+1) ----
#pragma unroll
    for (int kf = 0; kf < 2; ++kf) {
      bf16x8 af[2], bf[4];
#pragma unroll
      for (int m = 0; m < 2; ++m) af[m] = *(const bf16x8*)(As + aoff[m][kf]);
#pragma unroll
      for (int n = 0; n < 4; ++n) bf[n] = *(const bf16x8*)(Bs + boff[n][kf]);
#pragma unroll
      for (int m = 0; m < 2; ++m)
#pragma unroll
        for (int n = 0; n < 4; ++n)
          acc[m][n] = __builtin_amdgcn_mfma_f32_16x16x32_bf16(af[m], bf[n], acc[m][n], 0, 0, 0);
    }

    __syncthreads();   // bar2: all waves done reading As/Bs for tile t

    if (pre) {
      const size_t koff = (size_t)(t + 1) * 64;
#pragma unroll
      for (int r = 0; r < 4; ++r) gload16(gB[r] + koff, &Bs[lBo[r]]);  // B tile t+1
      u16x8 o0;
#pragma unroll
      for (int j = 0; j < 8; ++j) {
        float m0 = fmaxf(fmaxf(bf2f(a0[j]), bf2f(a1[j])), fmaxf(bf2f(a2[j]), bf2f(a3[j])));
        o0[j] = (unsigned short)(__float_as_uint(m0) >> 16);
      }
      *(u16x8*)(&As[awb]) = o0;                                        // A tile t+1
    }
  }

  // ---- epilogue: bf16 partials, Hp[split][4096][256] ----
  const int growb = bm * 64 + wr * 32 + ((lane >> 4) << 2);
  const int gcolb = wc * 64 + (lane & 15);
  unsigned short* Ho = Hp + (size_t)split * NROI * HID_;
#pragma unroll
  for (int m = 0; m < 2; ++m)
#pragma unroll
    for (int n = 0; n < 4; ++n)
#pragma unroll
      for (int j = 0; j < 4; ++j)
        Ho[(size_t)(growb + m * 16 + j) * HID_ + gcolb + n * 16] = f2bf(acc[m][n][j]);
}

// ============ head_loss: hfin + heads + per-ROI loss, one kernel ============
__global__ __launch_bounds__(256) void head_loss(
    const unsigned short* __restrict__ Hp, const float* __restrict__ b1,
    const unsigned short* __restrict__ WT, const float* __restrict__ Wbias,
    const int* __restrict__ labels, const float* __restrict__ tgt,
    float* __restrict__ out) {
  __shared__ __align__(16) unsigned char A_lds[64 * 512];  // 64 rois x 256ch bf16, swizzled
  __shared__ float O_lds[64][113];
  const int tid = threadIdx.x;
  const int roiBase = blockIdx.x * 64;

  // ---- phase 1: Hb tile = bf16(relu(sum_s Hp[s] + b1)) -> LDS ----
  {
    const int rl  = tid >> 2;           // 0..63
    const int seg = tid & 3;
    const size_t rowoff = (size_t)(roiBase + rl) * HID_;
#pragma unroll
    for (int g = 0; g < 8; ++g) {
      const int chunk = g * 4 + seg;    // 16B chunk id; consecutive tids -> consecutive chunks
      const int ch = chunk * 8;
      float s[8];
#pragma unroll
      for (int j = 0; j < 8; ++j) s[j] = b1[ch + j];
#pragma unroll
      for (int sp = 0; sp < NSPLIT; ++sp) {
        u16x8 v = *(const u16x8*)(Hp + (size_t)sp * NROI * HID_ + rowoff + ch);
#pragma unroll
        for (int j = 0; j < 8; ++j) s[j] += bf2f(v[j]);
      }
      u16x8 o;
#pragma unroll
      for (int j = 0; j < 8; ++j) o[j] = f2bf(fmaxf(s[j], 0.f));
      const int cb = chunk * 16;
      *(u16x8*)(&A_lds[rl * 512 + (cb ^ ((rl & 7) << 4))]) = o;
    }
  }
  __syncthreads();

  // ---- phase 2: MFMA, wave w -> rois [w*16, w*16+16), 7 col-tiles ----
  const int lane = tid & 63, w = tid >> 6;
  f32x4 acc[7] = {};
#pragma unroll
  for (int kf = 0; kf < 8; ++kf) {
    const int kb = kf * 64 + ((lane >> 4) << 4);
    const int arow = w * 16 + (lane & 15);
    bf16x8 av = *(const bf16x8*)(&A_lds[arow * 512 + (kb ^ ((arow & 7) << 4))]);
#pragma unroll
    for (int n = 0; n < 7; ++n) {
      bf16x8 bv = *(const bf16x8*)(WT + (size_t)(n * 16 + (lane & 15)) * HID_ + (kb >> 1));
      acc[n] = __builtin_amdgcn_mfma_f32_16x16x32_bf16(av, bv, acc[n], 0, 0, 0);
    }
  }
  {
    const int orow = w * 16 + ((lane >> 4) << 2);
#pragma unroll
    for (int n = 0; n < 7; ++n) {
      const int col = n * 16 + (lane & 15);
      const float bv = Wbias[col];
#pragma unroll
      for (int j = 0; j < 4; ++j) O_lds[orow + j][col] = acc[n][j] + bv;
    }
  }
  __syncthreads();

  // ---- phase 3: per-ROI loss (wave 0), block reduce, one atomicAdd ----
  if (tid < 64) {
    const int roi = roiBase + tid;
    const float* lg = O_lds[tid];
    float m = lg[0];
#pragma unroll
    for (int i = 1; i < NCLS_; ++i) m = fmaxf(m, lg[i]);
    float s = 0.f;
#pragma unroll
    for (int i = 0; i < NCLS_; ++i) s += expf(lg[i] - m);
    const float lse = m + logf(s);
    const int lab = labels[roi];
    float contrib = lse - lg[lab];
#pragma unroll
    for (int j = 0; j < 4; ++j) {
      float d = lg[NCLS_ + lab * 4 + j] - tgt[roi * 4 + j];
      float ad = fabsf(d);
      contrib += (ad < 1.f) ? 0.5f * d * d : ad - 0.5f;
    }
    contrib *= (1.0f / NROI);
#pragma unroll
    for (int off = 32; off > 0; off >>= 1) contrib += __shfl_down(contrib, off);
    if (tid == 0) atomicAdd(out, contrib);
  }
}

extern "C" void kernel_launch(void* const* d_in, const int* in_sizes, int n_in,
                              void* d_out, int out_size, void* d_ws, size_t ws_size,
                              hipStream_t stream) {
  const float* features = (const float*)d_in[0];
  const float* rois     = (const float*)d_in[1];
  const int*   labels   = (const int*)d_in[2];
  const float* tgt      = (const float*)d_in[3];
  const float* W1       = (const float*)d_in[4];
  const float* b1       = (const float*)d_in[5];
  const float* Wc       = (const float*)d_in[6];
  const float* bc       = (const float*)d_in[7];
  const float* Wb       = (const float*)d_in[8];
  const float* bb       = (const float*)d_in[9];

  char* ws = (char*)d_ws;
  unsigned short* Fb    = (unsigned short*)(ws);                // 20,480,000
  unsigned short* BTm   = (unsigned short*)(ws + 20480000);     // 6,422,528
  short4*         Bases = (short4*)(ws + 26902528);             // 1,605,632
  unsigned short* Hp    = (unsigned short*)(ws + 28508160);     // 33,554,432 (16 splits)
  unsigned short* WT    = (unsigned short*)(ws + 62062592);     // 57,344
  float*          Wbias = (float*)(ws + 62119936);              // 512 -> end 62,120,448

  hipMemsetAsync(d_out, 0, (size_t)out_size * sizeof(float), stream);

  hipLaunchKernelGGL(prep_all, dim3(NB_CVT + NB_TRN + NB_WPR + NB_BAS), dim3(256), 0, stream,
                     features, Fb, W1, BTm, Wc, bc, Wb, bb, WT, Wbias, rois, Bases);
  hipLaunchKernelGGL(gemm_fused, dim3(1024), dim3(512), 0, stream, Fb, Bases, BTm, Hp);
  hipLaunchKernelGGL(head_loss, dim3(NROI / 64), dim3(256), 0, stream,
                     Hp, b1, WT, Wbias, labels, tgt, (float*)d_out);
}

// Round 10
// 172.090 us; speedup vs baseline: 2.7154x; 2.7154x over previous
//
#include <hip/hip_runtime.h>

#define H_    200
#define W_    200
#define C_    256
#define NROI  4096
#define KDIM  12544   // 49*256
#define HID_  256
#define NCLS_ 21
#define NTASK (NROI * 49)
#define NSPLIT 8
#define NHEAD 112     // 21 + 84, padded to 7*16

typedef __bf16 bf16x8 __attribute__((ext_vector_type(8)));
typedef float  f32x4  __attribute__((ext_vector_type(4)));
typedef unsigned short u16x8 __attribute__((ext_vector_type(8)));

__device__ __forceinline__ unsigned short f2bf(float f) {
  unsigned u = __float_as_uint(f);
  return (unsigned short)((u + 0x7FFFu + ((u >> 16) & 1u)) >> 16);  // RNE, no NaN inputs
}
__device__ __forceinline__ float bf2f(unsigned short u) {
  return __uint_as_float(((unsigned)u) << 16);
}
__device__ __forceinline__ void gload16(const void* g, void* l) {
  __builtin_amdgcn_global_load_lds((const __attribute__((address_space(1))) unsigned int*)g,
                                   (__attribute__((address_space(3))) unsigned int*)l, 16, 0, 0);
}

// ================= prep_all: cvt + transpose_w1 + wprep + prep_bases =================
#define NB_CVT   2048
#define NB_TRN   3136   // 392 * 8
#define NB_WPR   112
#define NB_BAS   784    // NTASK/256

__global__ __launch_bounds__(256) void prep_all(
    const float* __restrict__ F, unsigned short* __restrict__ Fb,
    const float* __restrict__ W1, unsigned short* __restrict__ BT,
    const float* __restrict__ Wc, const float* __restrict__ bc,
    const float* __restrict__ Wb, const float* __restrict__ bb,
    unsigned short* __restrict__ WT, float* __restrict__ Wbias,
    const float* __restrict__ rois, short4* __restrict__ Bases) {
  __shared__ float tile[32][33];
  const int b = blockIdx.x;
  const int tid = threadIdx.x;

  if (b < NB_CVT) {
    // ---- features f32 -> bf16 ----
    const int n4 = (H_ * W_ * C_) / 4;
    for (int i = b * 256 + tid; i < n4; i += NB_CVT * 256) {
      float4 v = ((const float4*)F)[i];
      ushort4 o;
      o.x = f2bf(v.x); o.y = f2bf(v.y); o.z = f2bf(v.z); o.w = f2bf(v.w);
      ((ushort4*)Fb)[i] = o;
    }
  } else if (b < NB_CVT + NB_TRN) {
    // ---- W1 (K x N) -> BT (N x K) bf16 ----
    const int id = b - NB_CVT;
    const int k0 = (id % 392) * 32;
    const int n0 = (id / 392) * 32;
    const int tx = tid & 31;
    const int ty = tid >> 5;
#pragma unroll
    for (int i = 0; i < 4; ++i)
      tile[ty + 8 * i][tx] = W1[(size_t)(k0 + ty + 8 * i) * HID_ + n0 + tx];
    __syncthreads();
#pragma unroll
    for (int i = 0; i < 4; ++i) {
      const int n = ty + 8 * i;
      BT[(size_t)(n0 + n) * KDIM + k0 + tx] = f2bf(tile[tx][n]);
    }
  } else if (b < NB_CVT + NB_TRN + NB_WPR) {
    // ---- heads weights pack ----
    const int n = b - (NB_CVT + NB_TRN);
    const int k = tid;
    float v = 0.f;
    if (n < 21)       v = Wc[(size_t)k * NCLS_ + n];
    else if (n < 105) v = Wb[(size_t)k * (NCLS_ * 4) + (n - 21)];
    WT[(size_t)n * HID_ + k] = f2bf(v);
    if (k == 0) Wbias[n] = (n < 21) ? bc[n] : ((n < 105) ? bb[n - 21] : 0.f);
  } else {
    // ---- per-task gather bases ----
    const int task = (b - (NB_CVT + NB_TRN + NB_WPR)) * 256 + tid;
    const int roi  = task / 49;
    const int cell = task - roi * 49;
    const int py = cell / 7;
    const int px = cell - py * 7;

    float4 r = ((const float4*)rois)[roi];
    const float y1 = fminf(r.x, r.z), y2 = fmaxf(r.x, r.z);
    const float x1 = fminf(r.y, r.w), x2 = fmaxf(r.y, r.w);
    const float dy = __fsub_rn(y2, y1), dx = __fsub_rn(x2, x1);

    short v[4];
#pragma unroll
    for (int g = 0; g < 2; ++g) {
      float tyv = __fdiv_rn(__fadd_rn((float)(2 * py + g), 0.5f), 14.0f);
      float txv = __fdiv_rn(__fadd_rn((float)(2 * px + g), 0.5f), 14.0f);
      float ys = __fadd_rn(y1, __fmul_rn(dy, tyv));
      float xs = __fadd_rn(x1, __fmul_rn(dx, txv));
      int yi = (int)rintf(__fmul_rn(ys, 199.0f));
      int xi = (int)rintf(__fmul_rn(xs, 199.0f));
      v[g]     = (short)min(max(yi, 0), H_ - 1);
      v[2 + g] = (short)min(max(xi, 0), W_ - 1);
    }
    Bases[task] = make_short4(v[0], v[1], v[2], v[3]);
  }
}

// ============ gemm_fused: ROI-pool fused into A-staging; Hp[split] = X@W1 slice ============
// 64x256 tile, 512 threads (8 waves, 2x4 of 32x64), K-split 8 by cells. 80 KB LDS -> 2 blocks/CU.
// (round-8 proven config: 61.5 us, VGPR 56, no spill. Do NOT add a min-waves bound: the unified
//  VGPR/AGPR file makes a 64-reg budget spill catastrophically -- round-9 showed 884 MB scratch.)
__global__ __launch_bounds__(512) void gemm_fused(
    const unsigned short* __restrict__ Fb, const short4* __restrict__ Bases,
    const unsigned short* __restrict__ BT, unsigned short* __restrict__ Hp) {
  __shared__ __align__(16) unsigned char As[2][64 * 128];   // 16 KB
  __shared__ __align__(16) unsigned char Bs[2][256 * 128];  // 64 KB
  const int tid  = threadIdx.x;
  const int lane = tid & 63;
  const int wi   = tid >> 6;              // wave 0..7
  const int wr   = wi >> 2, wc = wi & 3;  // 2x4 wave grid, each 32x64

  const int split = blockIdx.x & 7;       // split-per-XCD: B K-slice shared on one L2
  const int bm    = blockIdx.x >> 3;      // 0..63
  const int c0 = (49 * split) >> 3;
  const int c1 = (49 * (split + 1)) >> 3;
  const int t0k = c0 * 4;
  const int nt  = (c1 - c0) * 4;          // 24 or 28

  // ---- A gather assignment: thread stages row rl, 8-ch group g8 (1 row, 4 loads/iter) ----
  const int rl = tid >> 3;                // 0..63
  const int g8 = tid & 7;
  const short4* bp = Bases + (size_t)(bm * 64 + rl) * 49;
  const int awb = rl * 128 + ((g8 * 16) ^ ((rl & 7) << 4));
  const unsigned short* fbg = Fb + g8 * 8;

  const unsigned short *p00, *p01, *p10, *p11;
#define SETPTRS(bv)                                        \
  p00 = fbg + ((size_t)((bv).x * W_ + (bv).z) * C_);       \
  p01 = fbg + ((size_t)((bv).x * W_ + (bv).w) * C_);       \
  p10 = fbg + ((size_t)((bv).y * W_ + (bv).z) * C_);       \
  p11 = fbg + ((size_t)((bv).y * W_ + (bv).w) * C_)

  // ---- B staging: linear LDS dest, inverse-swizzled global source ----
  const int srow  = lane >> 3;
  const int sbyte = ((lane & 7) << 4) ^ (srow << 4);
  const size_t kbase = (size_t)t0k * 64 + (sbyte >> 1);
  const unsigned short* gB[4];
  int lBo[4];
#pragma unroll
  for (int r = 0; r < 4; ++r) {
    const int row = r * 64 + wi * 8;
    gB[r]  = BT + (size_t)(row + srow) * KDIM + kbase;
    lBo[r] = row * 128;
  }

  // ---- LDS fragment-read offsets (swizzled) ----
  int aoff[2][2], boff[4][2];
#pragma unroll
  for (int kf = 0; kf < 2; ++kf) {
    const int kb = kf * 64 + ((lane >> 4) << 4);
#pragma unroll
    for (int m = 0; m < 2; ++m) {
      const int arow = wr * 32 + m * 16 + (lane & 15);
      aoff[m][kf] = arow * 128 + (kb ^ ((arow & 7) << 4));
    }
#pragma unroll
    for (int n = 0; n < 4; ++n) {
      const int brow = wc * 64 + n * 16 + (lane & 15);
      boff[n][kf] = brow * 128 + (kb ^ ((brow & 7) << 4));
    }
  }

  f32x4 acc[2][4] = {};

  // ---- prologue: stage tile 0 ----
  short4 nb = bp[c0];
  SETPTRS(nb);
  {
    const int pfc = (c0 + 1 < 49) ? c0 + 1 : 48;
    nb = bp[pfc];
  }
  {
    u16x8 a0 = *(const u16x8*)p00, a1 = *(const u16x8*)p01;
    u16x8 a2 = *(const u16x8*)p10, a3 = *(const u16x8*)p11;
    u16x8 o0;
#pragma unroll
    for (int j = 0; j < 8; ++j) {
      float m0 = fmaxf(fmaxf(bf2f(a0[j]), bf2f(a1[j])), fmaxf(bf2f(a2[j]), bf2f(a3[j])));
      o0[j] = (unsigned short)(__float_as_uint(m0) >> 16);
    }
    *(u16x8*)(&As[0][awb]) = o0;
#pragma unroll
    for (int r = 0; r < 4; ++r) gload16(gB[r], &Bs[0][lBo[r]]);
  }

  for (int t = 0; t < nt; ++t) {
    const int cur = t & 1;
    __syncthreads();   // tile cur ready (A ds_writes lgkm-drained, B gloads vmcnt-drained)

    const int pre = (t + 1 < nt);
    u16x8 a0, a1, a2, a3;
    if (pre) {
      const int tn = t + 1;
      const int qn = tn & 3;
      if (qn == 0) {
        SETPTRS(nb);                             // bases for cell c0+(tn>>2), prefetched
        const int cnx = c0 + (tn >> 2) + 1;
        const int pfc = (cnx < 49) ? cnx : 48;
        nb = bp[pfc];
      }
      const int qo = qn * 64;
      a0 = *(const u16x8*)(p00 + qo); a1 = *(const u16x8*)(p01 + qo);
      a2 = *(const u16x8*)(p10 + qo); a3 = *(const u16x8*)(p11 + qo);
      const size_t koff = (size_t)(t + 1) * 64;
      const int nx = cur ^ 1;
#pragma unroll
      for (int r = 0; r < 4; ++r) gload16(gB[r] + koff, &Bs[nx][lBo[r]]);
    }

    // ---- MFMA on tile cur (hides gather/gload latency) ----
    const unsigned char* Ab = As[cur];
    const unsigned char* Bb = Bs[cur];
#pragma unroll
    for (int kf = 0; kf < 2; ++kf) {
      bf16x8 af[2], bf[4];
#pragma unroll
      for (int m = 0; m < 2; ++m) af[m] = *(const bf16x8*)(Ab + aoff[m][kf]);
#pragma unroll
      for (int n = 0; n < 4; ++n) bf[n] = *(const bf16x8*)(Bb + boff[n][kf]);
#pragma unroll
      for (int m = 0; m < 2; ++m)
#pragma unroll
        for (int n = 0; n < 4; ++n)
          acc[m][n] = __builtin_amdgcn_mfma_f32_16x16x32_bf16(af[m], bf[n], acc[m][n], 0, 0, 0);
    }

    if (pre) {
      u16x8 o0;
#pragma unroll
      for (int j = 0; j < 8; ++j) {
        float m0 = fmaxf(fmaxf(bf2f(a0[j]), bf2f(a1[j])), fmaxf(bf2f(a2[j]), bf2f(a3[j])));
        o0[j] = (unsigned short)(__float_as_uint(m0) >> 16);
      }
      *(u16x8*)(&As[cur ^ 1][awb]) = o0;
    }
  }

  // ---- epilogue: bf16 partials, Hp[split][4096][256] ----
  const int growb = bm * 64 + wr * 32 + ((lane >> 4) << 2);
  const int gcolb = wc * 64 + (lane & 15);
  unsigned short* Ho = Hp + (size_t)split * NROI * HID_;
#pragma unroll
  for (int m = 0; m < 2; ++m)
#pragma unroll
    for (int n = 0; n < 4; ++n)
#pragma unroll
      for (int j = 0; j < 4; ++j)
        Ho[(size_t)(growb + m * 16 + j) * HID_ + gcolb + n * 16] = f2bf(acc[m][n][j]);
}

// ============ head_loss: hfin + heads + per-ROI loss; 16 rois/block, grid 256 ============
__global__ __launch_bounds__(256) void head_loss(
    const unsigned short* __restrict__ Hp, const float* __restrict__ b1,
    const unsigned short* __restrict__ WT, const float* __restrict__ Wbias,
    const int* __restrict__ labels, const float* __restrict__ tgt,
    float* __restrict__ out) {
  __shared__ __align__(16) unsigned char A_lds[16 * 512];  // 16 rois x 256ch bf16, swizzled
  __shared__ float O_lds[16][113];
  const int tid = threadIdx.x;
  const int roiBase = blockIdx.x * 16;

  // ---- phase 1: Hb tile = bf16(relu(sum_s Hp[s] + b1)) -> LDS ----
#pragma unroll
  for (int s = 0; s < 2; ++s) {
    const int slot  = tid + s * 256;      // 512 slots = 16 rois x 32 chunks
    const int rl    = slot >> 5;          // 0..15
    const int chunk = slot & 31;          // 16B chunk; consecutive tids -> consecutive chunks
    const int ch    = chunk * 8;
    const size_t rowoff = (size_t)(roiBase + rl) * HID_ + ch;
    float sum[8];
#pragma unroll
    for (int j = 0; j < 8; ++j) sum[j] = b1[ch + j];
#pragma unroll
    for (int sp = 0; sp < NSPLIT; ++sp) {
      u16x8 v = *(const u16x8*)(Hp + (size_t)sp * NROI * HID_ + rowoff);
#pragma unroll
      for (int j = 0; j < 8; ++j) sum[j] += bf2f(v[j]);
    }
    u16x8 o;
#pragma unroll
    for (int j = 0; j < 8; ++j) o[j] = f2bf(fmaxf(sum[j], 0.f));
    const int cb = chunk * 16;
    *(u16x8*)(&A_lds[rl * 512 + (cb ^ ((rl & 7) << 4))]) = o;
  }
  __syncthreads();

  // ---- phase 2: MFMA, wave w -> col-tiles {w, w+4} (wave 3: only tile 3) ----
  const int lane = tid & 63, w = tid >> 6;
  const int arow = lane & 15;
  f32x4 acc0 = {}, acc1 = {};
  const int n0t = w, n1t = w + 4;
  const bool has2 = (n1t < 7);
#pragma unroll
  for (int kf = 0; kf < 8; ++kf) {
    const int kb = kf * 64 + ((lane >> 4) << 4);
    bf16x8 av = *(const bf16x8*)(&A_lds[arow * 512 + (kb ^ ((arow & 7) << 4))]);
    bf16x8 bv0 = *(const bf16x8*)(WT + (size_t)(n0t * 16 + arow) * HID_ + (kb >> 1));
    acc0 = __builtin_amdgcn_mfma_f32_16x16x32_bf16(av, bv0, acc0, 0, 0, 0);
    if (has2) {
      bf16x8 bv1 = *(const bf16x8*)(WT + (size_t)(n1t * 16 + arow) * HID_ + (kb >> 1));
      acc1 = __builtin_amdgcn_mfma_f32_16x16x32_bf16(av, bv1, acc1, 0, 0, 0);
    }
  }
  {
    const int orow = (lane >> 4) << 2;    // roi-within-16 = orow + j
#pragma unroll
    for (int j = 0; j < 4; ++j) {
      const int col0 = n0t * 16 + arow;
      O_lds[orow + j][col0] = acc0[j] + Wbias[col0];
      if (has2) {
        const int col1 = n1t * 16 + arow;
        O_lds[orow + j][col1] = acc1[j] + Wbias[col1];
      }
    }
  }
  __syncthreads();

  // ---- phase 3: per-ROI loss (lanes 0-15 of wave 0), 16-wide shfl tree, one atomicAdd ----
  if (tid < 16) {
    const int roi = roiBase + tid;
    const float* lg = O_lds[tid];
    float m = lg[0];
#pragma unroll
    for (int i = 1; i < NCLS_; ++i) m = fmaxf(m, lg[i]);
    float s = 0.f;
#pragma unroll
    for (int i = 0; i < NCLS_; ++i) s += expf(lg[i] - m);
    const float lse = m + logf(s);
    const int lab = labels[roi];
    float contrib = lse - lg[lab];
#pragma unroll
    for (int j = 0; j < 4; ++j) {
      float d = lg[NCLS_ + lab * 4 + j] - tgt[roi * 4 + j];
      float ad = fabsf(d);
      contrib += (ad < 1.f) ? 0.5f * d * d : ad - 0.5f;
    }
    contrib *= (1.0f / NROI);
    contrib += __shfl_down(contrib, 8);
    contrib += __shfl_down(contrib, 4);
    contrib += __shfl_down(contrib, 2);
    contrib += __shfl_down(contrib, 1);
    if (tid == 0) atomicAdd(out, contrib);
  }
}

extern "C" void kernel_launch(void* const* d_in, const int* in_sizes, int n_in,
                              void* d_out, int out_size, void* d_ws, size_t ws_size,
                              hipStream_t stream) {
  const float* features = (const float*)d_in[0];
  const float* rois     = (const float*)d_in[1];
  const int*   labels   = (const int*)d_in[2];
  const float* tgt      = (const float*)d_in[3];
  const float* W1       = (const float*)d_in[4];
  const float* b1       = (const float*)d_in[5];
  const float* Wc       = (const float*)d_in[6];
  const float* bc       = (const float*)d_in[7];
  const float* Wb       = (const float*)d_in[8];
  const float* bb       = (const float*)d_in[9];

  char* ws = (char*)d_ws;
  unsigned short* Fb    = (unsigned short*)(ws);                // 20,480,000
  unsigned short* BTm   = (unsigned short*)(ws + 20480000);     // 6,422,528
  short4*         Bases = (short4*)(ws + 26902528);             // 1,605,632
  unsigned short* Hp    = (unsigned short*)(ws + 28508160);     // 16,777,216 (8 splits)
  unsigned short* WT    = (unsigned short*)(ws + 45285376);     // 57,344
  float*          Wbias = (float*)(ws + 45342720);              // 512 -> end 45,343,232

  hipMemsetAsync(d_out, 0, (size_t)out_size * sizeof(float), stream);

  hipLaunchKernelGGL(prep_all, dim3(NB_CVT + NB_TRN + NB_WPR + NB_BAS), dim3(256), 0, stream,
                     features, Fb, W1, BTm, Wc, bc, Wb, bb, WT, Wbias, rois, Bases);
  hipLaunchKernelGGL(gemm_fused, dim3(512), dim3(512), 0, stream, Fb, Bases, BTm, Hp);
  hipLaunchKernelGGL(head_loss, dim3(NROI / 16), dim3(256), 0, stream,
                     Hp, b1, WT, Wbias, labels, tgt, (float*)d_out);
}